// Round 4
// baseline (1563.334 us; speedup 1.0000x reference)
//
#include <hip/hip_runtime.h>
#include <hip/hip_bf16.h>

// Resubmission of round-2 source: round-3 bench failed with
// UnresponsiveContainer (infra), kernel never ran.

#define NN 100000   // nodes
#define NV 50000    // vars
#define NE 640000   // edges
#define FEAT 16
#define HD 128
#define NL 4
#define NI 20000    // n_int
#define KK 8
#define NPB 8       // nodes per block in GEMM-ish kernels

typedef __hip_bfloat16 bf16;

// ---------------- degree / norm ----------------
__global__ void k_deg_init(float* deg) {
    int i = blockIdx.x * blockDim.x + threadIdx.x;
    if (i < NN) deg[i] = 1.0f;
}

__global__ void k_deg_scatter(const int* __restrict__ ei, float* deg) {
    int e = blockIdx.x * blockDim.x + threadIdx.x;
    if (e < NE) atomicAdd(&deg[ei[NE + e]], 1.0f);
}

__global__ void k_deg_fin(const float* __restrict__ deg, float* dinv, float* selfn) {
    int i = blockIdx.x * blockDim.x + threadIdx.x;
    if (i < NN) {
        float d = deg[i];
        dinv[i]  = rsqrtf(d);
        selfn[i] = 1.0f / d;
    }
}

// ---------------- CSR build: prefix scan of in-degree counts ----------------
// one block of 256 threads; thread t owns a contiguous chunk of nodes.
#define CHUNK 391   // 256*391 = 100096 >= NN
__global__ void k_scan(const float* __restrict__ deg, int* __restrict__ row_ptr,
                       int* __restrict__ cnt) {
    __shared__ int sums[256];
    const int t = threadIdx.x;
    const int start = t * CHUNK;
    const int end = (start + CHUNK < NN) ? start + CHUNK : NN;
    int s = 0;
    for (int i = start; i < end; ++i) s += (int)deg[i] - 1;   // in-degree count
    sums[t] = s;
    __syncthreads();
    // Hillis-Steele inclusive scan over 256 partials
    for (int off = 1; off < 256; off <<= 1) {
        int v = (t >= off) ? sums[t - off] : 0;
        __syncthreads();
        sums[t] += v;
        __syncthreads();
    }
    int base = (t == 0) ? 0 : sums[t - 1];
    for (int i = start; i < end; ++i) {
        row_ptr[i] = base;
        base += (int)deg[i] - 1;
        cnt[i] = 0;
    }
    if (t == 255) row_ptr[NN] = base;   // == NE
}

__global__ void k_csr_fill(const int* __restrict__ ei,
                           const int* __restrict__ row_ptr, int* __restrict__ cnt,
                           const float* __restrict__ dinv,
                           int* __restrict__ col, float* __restrict__ wgt) {
    int e = blockIdx.x * blockDim.x + threadIdx.x;
    if (e >= NE) return;
    const int s = ei[e];
    const int d = ei[NE + e];
    const int pos = row_ptr[d] + atomicAdd(&cnt[d], 1);
    col[pos] = s;
    wgt[pos] = dinv[s] * dinv[d];
}

// ---------------- embedding MLP (16 -> 128 -> 128) ----------------
__global__ void k_embed(const float* __restrict__ x,
                        const float* __restrict__ vW1, const float* __restrict__ vb1,
                        const float* __restrict__ vW2, const float* __restrict__ vb2,
                        const float* __restrict__ cW1, const float* __restrict__ cb1,
                        const float* __restrict__ cW2, const float* __restrict__ cb2,
                        float* __restrict__ h) {
    const int j = threadIdx.x;                       // 0..127 (output col)
    const int n0 = blockIdx.x * NPB;
    __shared__ float xs[NPB][FEAT];
    __shared__ float hid[NPB][HD];

    const float *W1, *b1, *W2, *b2;
    if (n0 < NV) { W1 = vW1; b1 = vb1; W2 = vW2; b2 = vb2; }
    else         { W1 = cW1; b1 = cb1; W2 = cW2; b2 = cb2; }

    xs[j >> 4][j & 15] = x[(size_t)n0 * FEAT + j];
    __syncthreads();

    float acc[NPB];
    const float bb1 = b1[j];
#pragma unroll
    for (int m = 0; m < NPB; ++m) acc[m] = bb1;
#pragma unroll
    for (int f = 0; f < FEAT; ++f) {
        const float w = W1[f * HD + j];
#pragma unroll
        for (int m = 0; m < NPB; ++m) acc[m] += xs[m][f] * w;
    }
#pragma unroll
    for (int m = 0; m < NPB; ++m) hid[m][j] = fmaxf(acc[m], 0.0f);
    __syncthreads();

    const float bb2 = b2[j];
#pragma unroll
    for (int m = 0; m < NPB; ++m) acc[m] = bb2;
#pragma unroll 8
    for (int k = 0; k < HD; ++k) {
        const float w = W2[k * HD + j];
#pragma unroll
        for (int m = 0; m < NPB; ++m) acc[m] += hid[m][k] * w;
    }
#pragma unroll
    for (int m = 0; m < NPB; ++m) h[(size_t)(n0 + m) * HD + j] = acc[m];
}

// ---------------- hw = h @ conv_W[l]  (bf16 output) ----------------
__global__ void k_hw(const float* __restrict__ h, const float* __restrict__ W,
                     bf16* __restrict__ hw) {
    const int j = threadIdx.x;
    const int n0 = blockIdx.x * NPB;
    __shared__ float hs[NPB][HD];
#pragma unroll
    for (int m = 0; m < NPB; ++m) hs[m][j] = h[(size_t)(n0 + m) * HD + j];
    __syncthreads();

    float acc[NPB];
#pragma unroll
    for (int m = 0; m < NPB; ++m) acc[m] = 0.0f;
#pragma unroll 8
    for (int k = 0; k < HD; ++k) {
        const float w = W[k * HD + j];
#pragma unroll
        for (int m = 0; m < NPB; ++m) acc[m] += hs[m][k] * w;
    }
#pragma unroll
    for (int m = 0; m < NPB; ++m) hw[(size_t)(n0 + m) * HD + j] = __float2bfloat16(acc[m]);
}

// ---------------- gather + combine + refine MLP + residual ----------------
__global__ void k_combine(const bf16* __restrict__ hw,
                          const int* __restrict__ row_ptr,
                          const int* __restrict__ col,
                          const float* __restrict__ wgt,
                          const float* __restrict__ selfn,
                          const float* __restrict__ cb,
                          const float* __restrict__ W1, const float* __restrict__ b1,
                          const float* __restrict__ W2, const float* __restrict__ b2,
                          float* __restrict__ h) {
    const int j = threadIdx.x;
    const int n0 = blockIdx.x * NPB;
    __shared__ float hs[NPB][HD];
    __shared__ float hid[NPB][HD];

    const float cbj = cb[j];
#pragma unroll
    for (int m = 0; m < NPB; ++m) {
        const int node = n0 + m;
        float agg = __bfloat162float(hw[(size_t)node * HD + j]) * selfn[node] + cbj;
        const int e0 = row_ptr[node], e1 = row_ptr[node + 1];
        for (int e = e0; e < e1; ++e) {
            agg += wgt[e] * __bfloat162float(hw[(size_t)col[e] * HD + j]);
        }
        hs[m][j] = fmaxf(agg, 0.0f);
    }
    __syncthreads();

    float acc[NPB];
    const float bb1 = b1[j];
#pragma unroll
    for (int m = 0; m < NPB; ++m) acc[m] = bb1;
#pragma unroll 8
    for (int k = 0; k < HD; ++k) {
        const float w = W1[k * HD + j];
#pragma unroll
        for (int m = 0; m < NPB; ++m) acc[m] += hs[m][k] * w;
    }
#pragma unroll
    for (int m = 0; m < NPB; ++m) hid[m][j] = fmaxf(acc[m], 0.0f);
    __syncthreads();

    const float bb2 = b2[j];
#pragma unroll
    for (int m = 0; m < NPB; ++m) acc[m] = bb2;
#pragma unroll 8
    for (int k = 0; k < HD; ++k) {
        const float w = W2[k * HD + j];
#pragma unroll
        for (int m = 0; m < NPB; ++m) acc[m] += hid[m][k] * w;
    }
#pragma unroll
    for (int m = 0; m < NPB; ++m) h[(size_t)(n0 + m) * HD + j] += acc[m];
}

// ---------------- bernoulli head: (128 -> 64 -> 1) ----------------
__global__ void k_bern(const float* __restrict__ h,
                       const float* __restrict__ W1, const float* __restrict__ b1,
                       const float* __restrict__ W2, const float* __restrict__ b2,
                       float* __restrict__ out) {
    const long long t = (long long)blockIdx.x * blockDim.x + threadIdx.x;
    const int n = (int)(t >> 6);
    const int lane = (int)(t & 63);
    if (n >= NV) return;
    const float* hn = h + (size_t)n * HD;
    float acc = b1[lane];
#pragma unroll 8
    for (int k = 0; k < HD; ++k) acc += hn[k] * W1[k * 64 + lane];
    float p = fmaxf(acc, 0.0f) * W2[lane];
#pragma unroll
    for (int off = 32; off > 0; off >>= 1) p += __shfl_down(p, off);
    if (lane == 0) out[n] = p + b2[0];
}

// ---------------- categorical head: einsum nh,nhk->nk ----------------
__global__ void k_cat(const float* __restrict__ h,
                      const float* __restrict__ cW, const float* __restrict__ cb,
                      float* __restrict__ out) {
    const long long t = (long long)blockIdx.x * blockDim.x + threadIdx.x;
    const int n = (int)(t >> 6);
    const int lane = (int)(t & 63);
    if (n >= NI) return;
    const float* hn = h + (size_t)n * HD;
    float p[KK];
#pragma unroll
    for (int k = 0; k < KK; ++k) p[k] = 0.0f;
#pragma unroll
    for (int half = 0; half < 2; ++half) {
        const int hh = lane + 64 * half;
        const float vh = hn[hh];
        const float* wp = cW + ((size_t)n * HD + hh) * KK;
#pragma unroll
        for (int k = 0; k < KK; ++k) p[k] += vh * wp[k];
    }
#pragma unroll
    for (int k = 0; k < KK; ++k) {
#pragma unroll
        for (int off = 32; off > 0; off >>= 1) p[k] += __shfl_down(p[k], off);
    }
    if (lane == 0) {
#pragma unroll
        for (int k = 0; k < KK; ++k) out[NV + (size_t)n * KK + k] = p[k] + cb[(size_t)n * KK + k];
    }
}

extern "C" void kernel_launch(void* const* d_in, const int* in_sizes, int n_in,
                              void* d_out, int out_size, void* d_ws, size_t ws_size,
                              hipStream_t stream) {
    const float* x  = (const float*)d_in[0];
    const int*   ei = (const int*)d_in[1];   // int inputs arrive as int32!
    // d_in[2] = num_vars scalar (hardcoded NV)
    const float* ve_W1 = (const float*)d_in[3];
    const float* ve_b1 = (const float*)d_in[4];
    const float* ve_W2 = (const float*)d_in[5];
    const float* ve_b2 = (const float*)d_in[6];
    const float* ce_W1 = (const float*)d_in[7];
    const float* ce_b1 = (const float*)d_in[8];
    const float* ce_W2 = (const float*)d_in[9];
    const float* ce_b2 = (const float*)d_in[10];
    const float* conv_W = (const float*)d_in[11];
    const float* conv_b = (const float*)d_in[12];
    const float* ref_W1 = (const float*)d_in[13];
    const float* ref_b1 = (const float*)d_in[14];
    const float* ref_W2 = (const float*)d_in[15];
    const float* ref_b2 = (const float*)d_in[16];
    const float* bh_W1 = (const float*)d_in[17];
    const float* bh_b1 = (const float*)d_in[18];
    const float* bh_W2 = (const float*)d_in[19];
    const float* bh_b2 = (const float*)d_in[20];
    const float* cat_W = (const float*)d_in[21];
    const float* cat_b = (const float*)d_in[22];
    float* out = (float*)d_out;

    // ---- workspace layout (~80 MiB total) ----
    const size_t need = (size_t)(3 * NN + (NN + 1) + NN + 2 * NE) * 4
                      + (size_t)NN * HD * 4 + (size_t)NN * HD * 2;
    if (ws_size < need) return;   // disambiguate: absmax-fail instead of fault

    float* deg    = (float*)d_ws;                    // NN
    float* dinv   = deg + NN;                        // NN
    float* selfn  = dinv + NN;                       // NN
    int*   row_ptr= (int*)(selfn + NN);              // NN+1
    int*   cnt    = row_ptr + (NN + 1);              // NN
    int*   col    = cnt + NN;                        // NE
    float* wgt    = (float*)(col + NE);              // NE
    float* h      = wgt + NE;                        // NN*HD fp32
    bf16*  hwb    = (bf16*)(h + (size_t)NN * HD);    // NN*HD bf16

    // degree / norms / CSR
    k_deg_init<<<(NN + 255) / 256, 256, 0, stream>>>(deg);
    k_deg_scatter<<<(NE + 255) / 256, 256, 0, stream>>>(ei, deg);
    k_deg_fin<<<(NN + 255) / 256, 256, 0, stream>>>(deg, dinv, selfn);
    k_scan<<<1, 256, 0, stream>>>(deg, row_ptr, cnt);
    k_csr_fill<<<(NE + 255) / 256, 256, 0, stream>>>(ei, row_ptr, cnt, dinv, col, wgt);

    // embedding
    k_embed<<<NN / NPB, HD, 0, stream>>>(x, ve_W1, ve_b1, ve_W2, ve_b2,
                                         ce_W1, ce_b1, ce_W2, ce_b2, h);

    // conv layers
    for (int l = 0; l < NL; ++l) {
        k_hw<<<NN / NPB, HD, 0, stream>>>(h, conv_W + (size_t)l * HD * HD, hwb);
        k_combine<<<NN / NPB, HD, 0, stream>>>(hwb, row_ptr, col, wgt, selfn,
                                               conv_b + (size_t)l * HD,
                                               ref_W1 + (size_t)l * HD * HD,
                                               ref_b1 + (size_t)l * HD,
                                               ref_W2 + (size_t)l * HD * HD,
                                               ref_b2 + (size_t)l * HD,
                                               h);
    }

    // heads
    k_bern<<<(NV * 64) / 256, 256, 0, stream>>>(h, bh_W1, bh_b1, bh_W2, bh_b2, out);
    k_cat<<<(NI * 64) / 256, 256, 0, stream>>>(h, cat_W, cat_b, out);
}